// Round 8
// baseline (39.226 us; speedup 1.0000x reference)
//
#include <hip/hip_runtime.h>
#include <hip/hip_bf16.h>

#define BB 16
#define NN 16384
#define DD 128
#define CC 32
#define CHUNKS 32
#define NBLK (BB * CHUNKS)                  // 512
#define ROWS_PER_BLOCK (NN / CHUNKS)        // 512

// ---- PATH A workspace layout (floats) ----
#define P_SUMS 0                                   // NBLK*4096
#define P_CNTS ((size_t)NBLK * CC * DD)            // NBLK*32
#define LOSSP  (P_CNTS + (size_t)NBLK * CC)        // BB
#define CTR    (LOSSP + BB)                        // 1 (int)
#define WS_A_FLOATS (CTR + 1)

typedef float f32x16 __attribute__((ext_vector_type(16)));
typedef short short8 __attribute__((ext_vector_type(8)));

union FragU { short8 s; unsigned int u[4]; };
union BfU { __hip_bfloat162 h; unsigned int u; };

static __device__ inline float asfloat_u(unsigned int u) {
  union { unsigned int u; float f; } c; c.u = u; return c.f;
}

// ---------------- Kernel 1 (PATH A): MFMA segment sums ----------------------
// sums[c,d] = sum_n onehot[n,c] * x[n,d]  ==  onehot^T @ x : a GEMM.
// 512 blocks x 512 thr (8 waves). Wave (q,h): rows [q*128,q*128+128) of the
// block's 512 rows, cols [h*64, h*64+64). Per 16-row chunk: A-frag = onehot
// built in-regs from cids (exact in bf16), B = x split hi/lo bf16 (rel err
// ~5e-6), 4x mfma_f32_32x32x16_bf16 chained into fp32 AGPR accumulators.
// No LDS accumulator -> no RMW chain, no LDS-atomic wall; 16 waves/CU.
__global__ __launch_bounds__(512, 4) void seg_mfma_kernel(
    const float* __restrict__ x, const int* __restrict__ ids,
    float* __restrict__ outsums, float* __restrict__ outcnts,
    int* __restrict__ counter) {
  __shared__ float lsum[4][CC * DD];      // 64 KB epilogue fold buffer
  __shared__ float lcnt[CC];
  __shared__ int   lcid[ROWS_PER_BLOCK];  // 2 KB

  const int tid  = threadIdx.x;
  const int b    = blockIdx.y;
  const int row0 = blockIdx.x * ROWS_PER_BLOCK;
  const int lane = tid & 63;
  const int w    = tid >> 6;              // wave 0..7
  const int q    = w >> 1;                // row-quarter 0..3
  const int hh   = w & 1;                 // col-half 0..1
  const int half = lane >> 5;             // k-group within wave
  const int ln31 = lane & 31;
  const int slot = b * CHUNKS + blockIdx.x;
  const int* __restrict__ idrow = ids + (size_t)b * NN;

  if (tid < CC) lcnt[tid] = 0.f;
  lcid[tid] = idrow[row0 + tid];
  __syncthreads();
  atomicAdd(&lcnt[lcid[tid]], 1.f);

  // per-wave accumulators: 2 n-tiles of 32 cols
  f32x16 acc0, acc1;
#pragma unroll
  for (int i = 0; i < 16; ++i) { acc0[i] = 0.f; acc1[i] = 0.f; }

  // lane's load pointer: row (row0 + q*128 + half*8), col (hh*64 + ln31)
  const float* __restrict__ p0 =
      x + ((size_t)b * NN + row0 + q * 128 + half * 8) * DD + hh * 64 + ln31;
  const int kb0 = q * 128 + half * 8;   // lcid base for this wave/half

  float bufA[16], bufB[16];

#define LOADCH(BUF, j)                                                      \
  {                                                                         \
    _Pragma("unroll") for (int e = 0; e < 8; ++e) {                         \
      BUF[e]     = p0[((j) * 16 + e) * DD];                                 \
      BUF[8 + e] = p0[((j) * 16 + e) * DD + 32];                            \
    }                                                                       \
  }

#define PROCCH(BUF, j)                                                      \
  {                                                                         \
    FragU af;                                                               \
    _Pragma("unroll") for (int i = 0; i < 4; ++i) {                         \
      const int c0 = lcid[kb0 + (j) * 16 + 2 * i];                          \
      const int c1 = lcid[kb0 + (j) * 16 + 2 * i + 1];                      \
      const unsigned int lo = (c0 == ln31) ? 0x3F80u : 0u;                  \
      const unsigned int hi = (c1 == ln31) ? 0x3F80u : 0u;                  \
      af.u[i] = lo | (hi << 16);                                            \
    }                                                                       \
    FragU bh0, bl0, bh1, bl1;                                               \
    _Pragma("unroll") for (int i = 0; i < 4; ++i) {                         \
      {                                                                     \
        const float a0 = BUF[2 * i], a1 = BUF[2 * i + 1];                   \
        BfU hv; hv.h = __float22bfloat162_rn(make_float2(a0, a1));          \
        const float f0 = asfloat_u(hv.u << 16);                             \
        const float f1 = asfloat_u(hv.u & 0xFFFF0000u);                     \
        BfU lv; lv.h = __float22bfloat162_rn(make_float2(a0 - f0, a1 - f1));\
        bh0.u[i] = hv.u; bl0.u[i] = lv.u;                                   \
      }                                                                     \
      {                                                                     \
        const float a0 = BUF[8 + 2 * i], a1 = BUF[8 + 2 * i + 1];           \
        BfU hv; hv.h = __float22bfloat162_rn(make_float2(a0, a1));          \
        const float f0 = asfloat_u(hv.u << 16);                             \
        const float f1 = asfloat_u(hv.u & 0xFFFF0000u);                     \
        BfU lv; lv.h = __float22bfloat162_rn(make_float2(a0 - f0, a1 - f1));\
        bh1.u[i] = hv.u; bl1.u[i] = lv.u;                                   \
      }                                                                     \
    }                                                                       \
    acc0 = __builtin_amdgcn_mfma_f32_32x32x16_bf16(af.s, bh0.s, acc0, 0, 0, 0); \
    acc0 = __builtin_amdgcn_mfma_f32_32x32x16_bf16(af.s, bl0.s, acc0, 0, 0, 0); \
    acc1 = __builtin_amdgcn_mfma_f32_32x32x16_bf16(af.s, bh1.s, acc1, 0, 0, 0); \
    acc1 = __builtin_amdgcn_mfma_f32_32x32x16_bf16(af.s, bl1.s, acc1, 0, 0, 0); \
  }

  LOADCH(bufA, 0)
#pragma unroll
  for (int i = 0; i < 3; ++i) {
    LOADCH(bufB, 2 * i + 1)
    PROCCH(bufA, 2 * i)
    LOADCH(bufA, 2 * i + 2)
    PROCCH(bufB, 2 * i + 1)
  }
  LOADCH(bufB, 7)
  PROCCH(bufA, 6)
  PROCCH(bufB, 7)
#undef LOADCH
#undef PROCCH

  // epilogue: C-layout (m74/m101): col = lane&31, row = (r&3)+8*(r>>2)+4*half
#pragma unroll
  for (int r = 0; r < 16; ++r) {
    const int m = (r & 3) + 8 * (r >> 2) + 4 * half;
    lsum[q][m * DD + hh * 64 + ln31]      = acc0[r];
    lsum[q][m * DD + hh * 64 + 32 + ln31] = acc1[r];
  }
  __syncthreads();

  // fold 4 row-quarter slabs + plain-store 16 KB partial to own slot
  float* __restrict__ ps = outsums + (size_t)slot * CC * DD;
#pragma unroll
  for (int it = 0; it < 2; ++it) {
    const int i = (it * 512 + tid) * 4;
    float4 s0 = *reinterpret_cast<const float4*>(&lsum[0][i]);
    float4 s1 = *reinterpret_cast<const float4*>(&lsum[1][i]);
    float4 s2 = *reinterpret_cast<const float4*>(&lsum[2][i]);
    float4 s3 = *reinterpret_cast<const float4*>(&lsum[3][i]);
    float4 r = make_float4(s0.x + s1.x + s2.x + s3.x, s0.y + s1.y + s2.y + s3.y,
                           s0.z + s1.z + s2.z + s3.z, s0.w + s1.w + s2.w + s3.w);
    *reinterpret_cast<float4*>(&ps[i]) = r;
  }
  if (tid < CC) outcnts[slot * CC + tid] = lcnt[tid];
  if (slot == 0 && tid == 0)
    __hip_atomic_store(counter, 0, __ATOMIC_RELAXED, __HIP_MEMORY_SCOPE_AGENT);
}

// ---------------- Kernel 2 (PATH A): fused reduce + gram + final ------------
#define MSTR 132
__global__ __launch_bounds__(512) void finish_fused_kernel(
    const float* __restrict__ psums, const float* __restrict__ pcnts,
    float* __restrict__ lossp, int* __restrict__ counter,
    float* __restrict__ out) {
  __shared__ float mean[CC * MSTR];
  __shared__ float cnt[CC];
  __shared__ float red[512];

  const int b = blockIdx.x;
  const int tid = threadIdx.x;

  if (tid < CC) {
    float cs = 0.f;
#pragma unroll 8
    for (int c = 0; c < CHUNKS; ++c) cs += pcnts[(b * CHUNKS + c) * CC + tid];
    cnt[tid] = cs;
  }

  float4 a0 = make_float4(0.f, 0.f, 0.f, 0.f), a1 = a0;
  const size_t base = (size_t)b * CHUNKS * CC * DD + (size_t)tid * 8;
#pragma unroll 4
  for (int c = 0; c < CHUNKS; ++c) {
    const float4* p = reinterpret_cast<const float4*>(&psums[base + (size_t)c * CC * DD]);
    float4 q0 = p[0], q1 = p[1];
    a0.x += q0.x; a0.y += q0.y; a0.z += q0.z; a0.w += q0.w;
    a1.x += q1.x; a1.y += q1.y; a1.z += q1.z; a1.w += q1.w;
  }
  __syncthreads();

  {
    const int c = tid >> 4;
    const int d0 = (tid & 15) * 8;
    const float inv = 1.f / fmaxf(cnt[c], 1.f);
    float* mrow = &mean[c * MSTR + d0];
    mrow[0] = a0.x * inv; mrow[1] = a0.y * inv; mrow[2] = a0.z * inv; mrow[3] = a0.w * inv;
    mrow[4] = a1.x * inv; mrow[5] = a1.y * inv; mrow[6] = a1.z * inv; mrow[7] = a1.w * inv;
  }
  __syncthreads();

  float acc = 0.f;
  if (tid < (CC * (CC - 1)) / 2) {
    int c = 0, rem = tid;
    while (rem >= (CC - 1 - c)) { rem -= (CC - 1 - c); ++c; }
    int e = c + 1 + rem;
    const float4* mc = reinterpret_cast<const float4*>(&mean[c * MSTR]);
    const float4* me = reinterpret_cast<const float4*>(&mean[e * MSTR]);
    float dot = 0.f;
#pragma unroll 8
    for (int j = 0; j < DD / 4; ++j) {
      float4 u = mc[j], v = me[j];
      dot += u.x * v.x + u.y * v.y + u.z * v.z + u.w * v.w;
    }
    acc = fabsf(dot);
  }

  red[tid] = acc;
  __syncthreads();
  for (int s = 256; s > 0; s >>= 1) {
    if (tid < s) red[tid] += red[tid + s];
    __syncthreads();
  }

  if (tid == 0) {
    float valid = 0.f;
    for (int c = 0; c < CC; ++c) valid += (cnt[c] > 0.f) ? 1.f : 0.f;
    float denom = (valid > 1.f) ? valid * (valid - 1.f) * 0.5f : 1.f;
    float v = red[0] / denom * (1.0f / BB);
    __hip_atomic_store(&lossp[b], v, __ATOMIC_RELAXED, __HIP_MEMORY_SCOPE_AGENT);
    __threadfence();
    int old = __hip_atomic_fetch_add(counter, 1, __ATOMIC_ACQ_REL,
                                     __HIP_MEMORY_SCOPE_AGENT);
    if (old == BB - 1) {
      float s = 0.f;
#pragma unroll
      for (int i = 0; i < BB; ++i)
        s += __hip_atomic_load(&lossp[i], __ATOMIC_RELAXED,
                               __HIP_MEMORY_SCOPE_AGENT);
      out[0] = s;
    }
  }
}

// ---------------- PATH B fallback (proven R4 structure) ---------------------
#define ROWS_PER_WAVE_B 128
__global__ __launch_bounds__(256) void seg_sum_rmw_kernel(
    const float* __restrict__ x, const int* __restrict__ ids,
    float* __restrict__ gsums, float* __restrict__ gcounts) {
  __shared__ float lsum[4][CC * DD];
  __shared__ float lcnt[CC];
  __shared__ int   lcid[ROWS_PER_BLOCK];

  const int tid  = threadIdx.x;
  const int b    = blockIdx.y;
  const int row0 = blockIdx.x * ROWS_PER_BLOCK;
  const int lane = tid & 63;
  const int w    = tid >> 6;
  const int* __restrict__ idrow = ids + (size_t)b * NN;

  if (tid < CC) lcnt[tid] = 0.f;
  lcid[tid]       = idrow[row0 + tid];
  lcid[tid + 256] = idrow[row0 + tid + 256];
  {
    const float4 z4 = make_float4(0.f, 0.f, 0.f, 0.f);
#pragma unroll
    for (int i = 0; i < 16; ++i)
      *reinterpret_cast<float4*>(&lsum[w][(i * 64 + lane) * 4]) = z4;
  }
  __syncthreads();
  atomicAdd(&lcnt[lcid[tid]], 1.f);
  atomicAdd(&lcnt[lcid[tid + 256]], 1.f);

  const float2* __restrict__ x2 =
      reinterpret_cast<const float2*>(x + (size_t)b * NN * DD);
  const int wbase = w * ROWS_PER_WAVE_B;
  float* const slab = &lsum[w][0];

  for (int g = 0; g < ROWS_PER_WAVE_B / 8; ++g) {
    float2 v[8]; int cid[8];
#pragma unroll
    for (int k = 0; k < 8; ++k) {
      const int rl = wbase + g * 8 + k;
      v[k]   = x2[(size_t)(row0 + rl) * 64 + lane];
      cid[k] = lcid[rl];
    }
#pragma unroll
    for (int k = 0; k < 8; ++k) {
      float2* p = reinterpret_cast<float2*>(&slab[cid[k] * DD + 2 * lane]);
      float2 old = *p;
      *p = make_float2(old.x + v[k].x, old.y + v[k].y);
    }
  }
  __syncthreads();

  float* __restrict__ gs = gsums + (size_t)b * CC * DD;
  for (int i = tid; i < CC * DD; i += 256) {
    float s = lsum[0][i] + lsum[1][i] + lsum[2][i] + lsum[3][i];
    atomicAdd(&gs[i], s);
  }
  if (tid < CC) atomicAdd(&gcounts[b * CC + tid], lcnt[tid]);
}

__global__ __launch_bounds__(512) void finish_kernel_b(
    const float* __restrict__ gsums, const float* __restrict__ gcounts,
    float* __restrict__ out) {
  __shared__ float mean[CC * MSTR];
  __shared__ float cnt[CC];
  __shared__ float red[512];

  const int b = blockIdx.x;
  const int tid = threadIdx.x;

  if (tid < CC) cnt[tid] = gcounts[b * CC + tid];
  __syncthreads();

  for (int i = tid; i < CC * DD; i += 512) {
    int c = i >> 7;
    int d = i & 127;
    mean[c * MSTR + d] = gsums[(size_t)b * CC * DD + i] / fmaxf(cnt[c], 1.f);
  }
  __syncthreads();

  float acc = 0.f;
  if (tid < (CC * (CC - 1)) / 2) {
    int c = 0, rem = tid;
    while (rem >= (CC - 1 - c)) { rem -= (CC - 1 - c); ++c; }
    int e = c + 1 + rem;
    const float4* mc = reinterpret_cast<const float4*>(&mean[c * MSTR]);
    const float4* me = reinterpret_cast<const float4*>(&mean[e * MSTR]);
    float dot = 0.f;
#pragma unroll 8
    for (int j = 0; j < DD / 4; ++j) {
      float4 u = mc[j], v = me[j];
      dot += u.x * v.x + u.y * v.y + u.z * v.z + u.w * v.w;
    }
    acc = fabsf(dot);
  }

  red[tid] = acc;
  __syncthreads();
  for (int s = 256; s > 0; s >>= 1) {
    if (tid < s) red[tid] += red[tid + s];
    __syncthreads();
  }

  if (tid == 0) {
    float valid = 0.f;
    for (int c = 0; c < CC; ++c) valid += (cnt[c] > 0.f) ? 1.f : 0.f;
    float denom = (valid > 1.f) ? valid * (valid - 1.f) * 0.5f : 1.f;
    atomicAdd(out, red[0] / denom * (1.0f / BB));
  }
}

extern "C" void kernel_launch(void* const* d_in, const int* in_sizes, int n_in,
                              void* d_out, int out_size, void* d_ws, size_t ws_size,
                              hipStream_t stream) {
  const float* x   = (const float*)d_in[0];
  const int*   ids = (const int*)d_in[1];
  float* out = (float*)d_out;
  float* ws  = (float*)d_ws;

  dim3 grid1(CHUNKS, BB);
  if (ws_size >= WS_A_FLOATS * sizeof(float)) {
    float* psums = ws + P_SUMS;
    float* pcnts = ws + P_CNTS;
    float* lossp = ws + LOSSP;
    int*   ctr   = (int*)(ws + CTR);
    seg_mfma_kernel<<<grid1, 512, 0, stream>>>(x, ids, psums, pcnts, ctr);
    finish_fused_kernel<<<BB, 512, 0, stream>>>(psums, pcnts, lossp, ctr, out);
  } else {
    float* gsums   = ws;
    float* gcounts = gsums + (size_t)BB * CC * DD;
    const size_t wsb = ((size_t)BB * CC * DD + (size_t)BB * CC) * sizeof(float);
    hipMemsetAsync(d_ws, 0, wsb, stream);
    hipMemsetAsync(d_out, 0, sizeof(float), stream);
    seg_sum_rmw_kernel<<<grid1, 256, 0, stream>>>(x, ids, gsums, gcounts);
    finish_kernel_b<<<BB, 512, 0, stream>>>(gsums, gcounts, out);
  }
}